// Round 4
// baseline (523.954 us; speedup 1.0000x reference)
//
#include <hip/hip_runtime.h>
#include <hip/hip_bf16.h>
#include <stdint.h>

#define S   384
#define CM  256
#define CH  32
#define CZ  128
#define BB  256     // MSA depth b = K of GEMM1
#define EPS 1e-5f

typedef __attribute__((ext_vector_type(8))) short bf16x8;   // 8 bf16 = 4 VGPRs
typedef __attribute__((ext_vector_type(4))) float f32x4;

// workspace layout (bytes) — mnorm eliminated (rmsnorm fused into k2)
#define OFF_QT    0u                       // [12288][256] bf16 = 6291456  (row = i*32+c, col = b)
#define OFF_KT    6291456u                 // [12288][256] bf16            (row = j*32+d, col = b)
#define OFF_WT    (OFF_KT + 6291456u)      // [64][256] bf16 = 32768
#define OFF_WOT   (OFF_WT + 32768u)        // [128][1024] bf16 = 262144    WoTp[e][d*32+c] = Wo[c*32+d][e]

__device__ __forceinline__ unsigned short f2bf(float x) {
  union { __hip_bfloat16 h; unsigned short u; } v;
  v.h = __float2bfloat16(x);
  return v.u;
}

// async global->LDS, 16B per lane. lds offset wave-uniform; HW scatters lane L to base + L*16.
__device__ __forceinline__ void gload_lds16(const void* g, char* smem, uint32_t lds_off_uniform) {
  uint32_t l32 = (uint32_t)(uintptr_t)(smem + lds_off_uniform);
  __builtin_amdgcn_global_load_lds(
      (const __attribute__((address_space(1))) uint32_t*)(uintptr_t)g,
      (__attribute__((address_space(3))) uint32_t*)(uintptr_t)l32,
      16, 0, 0);
}

// ---------------- K0: prep WT (q|k concat, transposed) and WoTp (transposed + k-reordered) ----------
__global__ void k0_prep(const float* __restrict__ Wq, const float* __restrict__ Wk,
                        const float* __restrict__ Wo,
                        unsigned short* __restrict__ WTg, unsigned short* __restrict__ WoTg) {
  int idx = blockIdx.x * 256 + threadIdx.x;
  if (idx < 64 * 256) {
    int c = idx >> 8, t = idx & 255;
    float v = (c < 32) ? Wq[t * 32 + c] : Wk[t * 32 + (c - 32)];
    WTg[c * 256 + t] = f2bf(v);
  }
  int j = idx - 64 * 256;
  if (j >= 0 && j < 128 * 1024) {
    int e = j >> 10, dc = j & 1023;       // dc = d*32 + c  (stage-2 k order)
    int c = dc & 31, d = dc >> 5;
    WoTg[e * 1024 + dc] = f2bf(Wo[(c * 32 + d) * 128 + e]);
  }
}

// ---------------- K2: fused rmsnorm + projection GEMM, writes qT/kT transposed -----------------------
// block owns rows (b0+bl, i0+il), bl in 32, il in 4 — DISJOINT across blocks, so rmsnorm is local.
__global__ __launch_bounds__(256, 2) void k2_proj(const float* __restrict__ m,
                                                  const float* __restrict__ gin,
                                                  const unsigned short* __restrict__ WTg,
                                                  const float* __restrict__ bq,
                                                  const float* __restrict__ bk,
                                                  unsigned short* __restrict__ qT,
                                                  unsigned short* __restrict__ kT) {
  // LDS: A [128][64] bf16 swz @0 (16KB) | WT [64][256] swz @16384 (32KB) |
  //      scl[128] f32 @49152 (512B) | Cbuf [128][72] bf16 @49664 (18KB)
  __shared__ char smem[49664 + 18432] __attribute__((aligned(16)));
  const int tid = threadIdx.x;
  const int w = tid >> 6, lane = tid & 63;
  const int mlo = lane & 15, quad = lane >> 4;
  const int i0 = blockIdx.x * 4, b0 = blockIdx.y * 32;
  float* scl = (float*)(smem + 49152);

  // stage full WT once (swizzled 16B blocks, rows of 512B)
  #pragma unroll
  for (int s = 0; s < 8; ++s) {
    int C0 = (w * 8 + s) * 2;
    int c = C0 + (lane >> 5);
    int j = lane & 31;
    int t8 = (j & ~7) | ((j & 7) ^ (c & 7));
    gload_lds16(WTg + c * 256 + t8 * 8, smem, 16384u + (uint32_t)C0 * 512u);
  }

  // -------- phase A: per-row sum of squares (fp32), 2 threads per row, 128 floats each --------
  const int rowA = tid >> 1, halfA = tid & 1;
  const int growA = (b0 + (rowA >> 2)) * S + i0 + (rowA & 3);
  {
    const float4* p = (const float4*)(m + (size_t)growA * CM + halfA * 128);
    float ss = 0.f;
    #pragma unroll 8
    for (int q4 = 0; q4 < 32; ++q4) {     // 32 x float4 = 128 floats (FIX: was 8)
      float4 x = p[q4];
      ss += x.x * x.x + x.y * x.y + x.z * x.z + x.w * x.w;
    }
    ss += __shfl_xor(ss, 1, 64);
    if (!halfA) scl[rowA] = rsqrtf(ss * (1.f / 256.f) + EPS);
  }

  f32x4 acc[2][4];
  #pragma unroll
  for (int p = 0; p < 2; ++p)
    #pragma unroll
    for (int q = 0; q < 4; ++q) acc[p][q] = (f32x4)0.f;

  for (int kb = 0; kb < 4; ++kb) {
    __syncthreads();
    // -------- phase B: load m chunk (L2-hot 2nd read), scale, cvt bf16, ds_write A-tile --------
    {
      const int row = tid >> 1, tk0 = (tid & 1) * 32;
      const float4* pB = (const float4*)(m + (size_t)growA * CM + kb * 64 + tk0);
      const float4* pG = (const float4*)(gin + kb * 64 + tk0);
      float sc = scl[row];
      #pragma unroll
      for (int u = 0; u < 4; ++u) {
        float4 x0 = pB[u * 2], x1 = pB[u * 2 + 1];
        float4 g0 = pG[u * 2], g1 = pG[u * 2 + 1];
        union { unsigned short h[8]; int4 q; } pk;
        pk.h[0] = f2bf(x0.x * sc * g0.x); pk.h[1] = f2bf(x0.y * sc * g0.y);
        pk.h[2] = f2bf(x0.z * sc * g0.z); pk.h[3] = f2bf(x0.w * sc * g0.w);
        pk.h[4] = f2bf(x1.x * sc * g1.x); pk.h[5] = f2bf(x1.y * sc * g1.y);
        pk.h[6] = f2bf(x1.z * sc * g1.z); pk.h[7] = f2bf(x1.w * sc * g1.w);
        int blkid = (((tid & 1) * 4 + u) ^ (row & 7));
        *(int4*)(smem + row * 128 + blkid * 16) = pk.q;
      }
    }
    __syncthreads();
    #pragma unroll
    for (int ks = 0; ks < 2; ++ks) {
      bf16x8 af[2], bfr[4];
      int k8 = ks * 4 + quad;
      #pragma unroll
      for (int fm = 0; fm < 2; ++fm) {
        int mm = w * 32 + fm * 16 + mlo;
        af[fm] = *(const bf16x8*)(smem + mm * 128 + ((k8 ^ (mm & 7)) * 16));
      }
      #pragma unroll
      for (int fn = 0; fn < 4; ++fn) {
        int c = fn * 16 + mlo;
        int t8 = kb * 8 + ks * 4 + quad;
        bfr[fn] = *(const bf16x8*)(smem + 16384 + c * 512 + (((t8 & ~7) | ((t8 & 7) ^ (c & 7))) * 16));
      }
      #pragma unroll
      for (int fm = 0; fm < 2; ++fm)
        #pragma unroll
        for (int fn = 0; fn < 4; ++fn)
          acc[fm][fn] = __builtin_amdgcn_mfma_f32_16x16x32_bf16(af[fm], bfr[fn], acc[fm][fn], 0, 0, 0);
    }
  }
  __syncthreads();
  unsigned short* Cl = (unsigned short*)(smem + 49664);
  #pragma unroll
  for (int fm = 0; fm < 2; ++fm)
    #pragma unroll
    for (int fn = 0; fn < 4; ++fn) {
      int cc = fn * 16 + mlo;
      float bias = (cc < 32) ? bq[cc] : bk[cc - 32];
      #pragma unroll
      for (int r = 0; r < 4; ++r) {
        int rr = w * 32 + fm * 16 + quad * 4 + r;
        Cl[rr * 72 + cc] = f2bf(acc[fm][fn][r] + bias);
      }
    }
  __syncthreads();
  {
    int il = tid >> 6, cc = tid & 63;
    unsigned short* dst = (cc < 32) ? (qT + ((i0 + il) * 32 + cc) * BB + b0)
                                    : (kT + ((i0 + il) * 32 + (cc - 32)) * BB + b0);
    #pragma unroll
    for (int v = 0; v < 4; ++v) {
      union { unsigned short h[8]; int4 q; } u;
      #pragma unroll
      for (int x = 0; x < 8; ++x) u.h[x] = Cl[((v * 8 + x) * 4 + il) * 72 + cc];
      *(int4*)(dst + v * 8) = u.q;
    }
  }
}

// ---------------- K3: fused O-tile GEMM (K=b) -> @Wo + bo -> rmsnorm -> z ---------------------------
// 256 threads = 4 waves in 2x2 (wm x wn); wave sub-tile 64x64, frags 4x4 (m97 shape).
// XCD swizzle: consecutive blockIdx.x -> XCD round-robin; give XCD x the ti-panel [x*12, x*12+12)
// so its resident working set (qT panel ~770KB + kT ~128KB + WoT 256KB) fits the 4MB per-XCD L2.
__global__ __launch_bounds__(256, 4) void k3_fused(const unsigned short* __restrict__ qT,
                                                   const unsigned short* __restrict__ kT,
                                                   const unsigned short* __restrict__ WoTp,
                                                   const float* __restrict__ bo,
                                                   const float* __restrict__ gout,
                                                   float* __restrict__ out) {
  // LDS 32KB: [0,16384) A-tile [128][64] swz | [16384,32768) B-tile; after GEMM1 both alias
  // O_lds [16 ij][1024 k2'] bf16 (k2' = d*32+c), swizzled. After stage-2, first 320B alias red/scl.
  __shared__ char smem[32768] __attribute__((aligned(16)));
  const int tid = threadIdx.x;
  const int w = tid >> 6, lane = tid & 63;
  const int wm = w & 1, wn = w >> 1;
  const int bx = blockIdx.x;
  const int ti = (bx & 7) * 12 + (bx >> 3);   // 96 = 8 XCDs x 12-tile panels
  const int tj = blockIdx.y;
  const int mlo = lane & 15, quad = lane >> 4;

  f32x4 acc[4][4];
  #pragma unroll
  for (int p = 0; p < 4; ++p)
    #pragma unroll
    for (int q = 0; q < 4; ++q) acc[p][q] = (f32x4)0.f;

  // -------- GEMM1: O[m][n] = sum_b qT[ti*128+m][b] * kT[tj*128+n][b], K=256, BK=64 --------
  for (int kb = 0; kb < 4; ++kb) {
    __syncthreads();
    #pragma unroll
    for (int s = 0; s < 4; ++s) {
      int r = w * 32 + s * 8 + (lane >> 3);
      int k8 = (lane & 7) ^ (r & 7);          // source-permute => swizzled LDS, linear dest
      gload_lds16(qT + (ti * 128 + r) * BB + kb * 64 + k8 * 8, smem, (uint32_t)(w * 32 + s * 8) * 128u);
      gload_lds16(kT + (tj * 128 + r) * BB + kb * 64 + k8 * 8, smem, 16384u + (uint32_t)(w * 32 + s * 8) * 128u);
    }
    asm volatile("s_waitcnt vmcnt(0)" ::: "memory");
    __syncthreads();
    #pragma unroll
    for (int ks = 0; ks < 2; ++ks) {
      bf16x8 af[4], bfr[4];
      int k8 = ks * 4 + quad;
      #pragma unroll
      for (int f = 0; f < 4; ++f) {
        int mm = wm * 64 + f * 16 + mlo;
        af[f] = *(const bf16x8*)(smem + mm * 128 + ((k8 ^ (mm & 7)) * 16));
        int nn = wn * 64 + f * 16 + mlo;
        bfr[f] = *(const bf16x8*)(smem + 16384 + nn * 128 + ((k8 ^ (nn & 7)) * 16));
      }
      #pragma unroll
      for (int fm = 0; fm < 4; ++fm)
        #pragma unroll
        for (int fn = 0; fn < 4; ++fn)
          acc[fm][fn] = __builtin_amdgcn_mfma_f32_16x16x32_bf16(af[fm], bfr[fn], acc[fm][fn], 0, 0, 0);
    }
  }
  __syncthreads();   // A/B tiles consumed; O_lds aliases them

  // -------- O (C-layout regs) -> O_lds[ij][k2'] bf16, k2' = d*32 + c; packed 8B writes --------
  #pragma unroll
  for (int fm = 0; fm < 4; ++fm)
    #pragma unroll
    for (int fn = 0; fn < 4; ++fn) {
      int col = wn * 64 + fn * 16 + mlo;                 // n = jloc*32 + d
      int row0 = wm * 64 + fm * 16 + quad * 4;           // m = iloc*32 + c (r contiguous in c)
      int ij = (row0 >> 5) * 4 + (col >> 5);             // iloc*4 + jloc
      int k20 = (col & 31) * 32 + (row0 & 31);           // d*32 + c
      int blk = k20 >> 3;
      int off = ij * 2048 + (((blk & ~7) | ((blk & 7) ^ (ij & 7))) * 16) + (k20 & 7) * 2;
      union { unsigned short h[4]; uint2 u; } pk;
      #pragma unroll
      for (int r = 0; r < 4; ++r) pk.h[r] = f2bf(acc[fm][fn][r]);
      *(uint2*)(smem + off) = pk.u;
    }
  __syncthreads();

  // -------- stage 2: z[16 ij][128 e] = O @ Wo; wave w owns e in [w*32, w*32+32) --------
  const int e0 = w * 32 + mlo, e1 = w * 32 + 16 + mlo;
  const unsigned short* wrow0 = WoTp + (size_t)e0 * 1024;
  const unsigned short* wrow1 = WoTp + (size_t)e1 * 1024;
  f32x4 acc2[4];
  #pragma unroll
  for (int p = 0; p < 4; ++p) acc2[p] = (f32x4)0.f;
  #pragma unroll 8
  for (int kk = 0; kk < 32; ++kk) {
    int k = kk * 32 + quad * 8;
    int blk = kk * 4 + quad;
    bf16x8 a = *(const bf16x8*)(smem + mlo * 2048 + (((blk & ~7) | ((blk & 7) ^ (mlo & 7))) * 16));
    bf16x8 b0v = *(const bf16x8*)(wrow0 + k);
    bf16x8 b1v = *(const bf16x8*)(wrow1 + k);
    acc2[kk & 1]       = __builtin_amdgcn_mfma_f32_16x16x32_bf16(a, b0v, acc2[kk & 1], 0, 0, 0);
    acc2[2 + (kk & 1)] = __builtin_amdgcn_mfma_f32_16x16x32_bf16(a, b1v, acc2[2 + (kk & 1)], 0, 0, 0);
  }

  // -------- + bo, rmsnorm over e per (i,j), write out --------
  float bv0 = bo[e0], bv1 = bo[e1], gv0 = gout[e0], gv1 = gout[e1];
  float v0[4], v1[4], sq[4];
  #pragma unroll
  for (int r = 0; r < 4; ++r) {
    v0[r] = acc2[0][r] + acc2[1][r] + bv0;
    v1[r] = acc2[2][r] + acc2[3][r] + bv1;
    sq[r] = v0[r] * v0[r] + v1[r] * v1[r];
  }
  #pragma unroll
  for (int o = 1; o < 16; o <<= 1)
    #pragma unroll
    for (int r = 0; r < 4; ++r) sq[r] += __shfl_xor(sq[r], o, 64);

  __syncthreads();                       // O_lds reads done; red/scl alias smem
  float* red = (float*)smem;             // [16 ij][4 wave]
  float* sclp = (float*)(smem + 256);    // [16]
  if (mlo == 0) {
    #pragma unroll
    for (int r = 0; r < 4; ++r) red[(quad * 4 + r) * 4 + w] = sq[r];
  }
  __syncthreads();
  if (tid < 16) {
    float s = red[tid * 4] + red[tid * 4 + 1] + red[tid * 4 + 2] + red[tid * 4 + 3];
    sclp[tid] = rsqrtf(s * (1.f / 128.f) + EPS);
  }
  __syncthreads();
  #pragma unroll
  for (int r = 0; r < 4; ++r) {
    int ij = quad * 4 + r;
    float sc = sclp[ij];
    int gi = ti * 4 + quad, gj = tj * 4 + r;
    float* dst = out + ((size_t)gi * S + gj) * CZ;
    dst[e0] = v0[r] * sc * gv0;
    dst[e1] = v1[r] * sc * gv1;
  }
}

// ---------------------------------------------------------------------------------------------------
extern "C" void kernel_launch(void* const* d_in, const int* in_sizes, int n_in,
                              void* d_out, int out_size, void* d_ws, size_t ws_size,
                              hipStream_t stream) {
  const float* m    = (const float*)d_in[0];
  const float* gin  = (const float*)d_in[1];
  const float* Wq   = (const float*)d_in[2];
  const float* bq   = (const float*)d_in[3];
  const float* Wk   = (const float*)d_in[4];
  const float* bk   = (const float*)d_in[5];
  const float* Wo   = (const float*)d_in[6];
  const float* bo   = (const float*)d_in[7];
  const float* gout = (const float*)d_in[8];

  char* ws = (char*)d_ws;
  unsigned short* qT    = (unsigned short*)(ws + OFF_QT);
  unsigned short* kT    = (unsigned short*)(ws + OFF_KT);
  unsigned short* WTg   = (unsigned short*)(ws + OFF_WT);
  unsigned short* WoTp  = (unsigned short*)(ws + OFF_WOT);
  float* out = (float*)d_out;

  hipLaunchKernelGGL(k0_prep, dim3(576), dim3(256), 0, stream, Wq, Wk, Wo, WTg, WoTp);
  hipLaunchKernelGGL(k2_proj, dim3(96, 8), dim3(256), 0, stream, m, gin, WTg, bq, bk, qT, kT);
  hipLaunchKernelGGL(k3_fused, dim3(96, 96), dim3(256), 0, stream, qT, kT, WoTp, bo, gout, out);
}

// Round 5
// 410.864 us; speedup vs baseline: 1.2752x; 1.2752x over previous
//
#include <hip/hip_runtime.h>
#include <hip/hip_bf16.h>
#include <stdint.h>

#define S   384
#define CM  256
#define CH  32
#define CZ  128
#define BB  256     // MSA depth b = K of GEMM1
#define EPS 1e-5f

typedef __attribute__((ext_vector_type(8))) short bf16x8;   // 8 bf16 = 4 VGPRs
typedef __attribute__((ext_vector_type(4))) float f32x4;

// workspace layout (bytes)
#define OFF_QT    0u                       // [12288][256] bf16 = 6291456  (row = i*32+c, col = b)
#define OFF_KT    6291456u                 // [12288][256] bf16            (row = j*32+d, col = b)
#define OFF_WT    (OFF_KT + 6291456u)      // [64][256] bf16 = 32768
#define OFF_WOT   (OFF_WT + 32768u)        // [128][1024] bf16 = 262144    WoTp[e][d*32+c] = Wo[c*32+d][e]

__device__ __forceinline__ unsigned short f2bf(float x) {
  union { __hip_bfloat16 h; unsigned short u; } v;
  v.h = __float2bfloat16(x);
  return v.u;
}

// async global->LDS, 16B per lane. lds offset wave-uniform; HW scatters lane L to base + L*16.
__device__ __forceinline__ void gload_lds16(const void* g, char* smem, uint32_t lds_off_uniform) {
  uint32_t l32 = (uint32_t)(uintptr_t)(smem + lds_off_uniform);
  __builtin_amdgcn_global_load_lds(
      (const __attribute__((address_space(1))) uint32_t*)(uintptr_t)g,
      (__attribute__((address_space(3))) uint32_t*)(uintptr_t)l32,
      16, 0, 0);
}

// ---------------- K0: prep WT (q|k concat, transposed) and WoTp (transposed + k-reordered) ----------
__global__ void k0_prep(const float* __restrict__ Wq, const float* __restrict__ Wk,
                        const float* __restrict__ Wo,
                        unsigned short* __restrict__ WTg, unsigned short* __restrict__ WoTg) {
  int idx = blockIdx.x * 256 + threadIdx.x;
  if (idx < 64 * 256) {
    int c = idx >> 8, t = idx & 255;
    float v = (c < 32) ? Wq[t * 32 + c] : Wk[t * 32 + (c - 32)];
    WTg[c * 256 + t] = f2bf(v);
  }
  int j = idx - 64 * 256;
  if (j >= 0 && j < 128 * 1024) {
    int e = j >> 10, dc = j & 1023;       // dc = d*32 + c  (stage-2 k order)
    int c = dc & 31, d = dc >> 5;
    WoTg[e * 1024 + dc] = f2bf(Wo[(c * 32 + d) * 128 + e]);
  }
}

// ---------------- K2: fused rmsnorm + projection GEMM, writes qT/kT transposed -----------------------
__global__ __launch_bounds__(256, 2) void k2_proj(const float* __restrict__ m,
                                                  const float* __restrict__ gin,
                                                  const unsigned short* __restrict__ WTg,
                                                  const float* __restrict__ bq,
                                                  const float* __restrict__ bk,
                                                  unsigned short* __restrict__ qT,
                                                  unsigned short* __restrict__ kT) {
  // LDS: A [128][64] bf16 swz @0 (16KB) | WT [64][256] swz @16384 (32KB) |
  //      scl[128] f32 @49152 (512B) | Cbuf [128][72] bf16 @49664 (18KB)
  __shared__ char smem[49664 + 18432] __attribute__((aligned(16)));
  const int tid = threadIdx.x;
  const int w = tid >> 6, lane = tid & 63;
  const int mlo = lane & 15, quad = lane >> 4;
  const int i0 = blockIdx.x * 4, b0 = blockIdx.y * 32;
  float* scl = (float*)(smem + 49152);

  #pragma unroll
  for (int s = 0; s < 8; ++s) {
    int C0 = (w * 8 + s) * 2;
    int c = C0 + (lane >> 5);
    int j = lane & 31;
    int t8 = (j & ~7) | ((j & 7) ^ (c & 7));
    gload_lds16(WTg + c * 256 + t8 * 8, smem, 16384u + (uint32_t)C0 * 512u);
  }

  // phase A: per-row sum of squares (fp32), 2 threads per row, 128 floats each
  const int rowA = tid >> 1, halfA = tid & 1;
  const int growA = (b0 + (rowA >> 2)) * S + i0 + (rowA & 3);
  {
    const float4* p = (const float4*)(m + (size_t)growA * CM + halfA * 128);
    float ss = 0.f;
    #pragma unroll 8
    for (int q4 = 0; q4 < 32; ++q4) {
      float4 x = p[q4];
      ss += x.x * x.x + x.y * x.y + x.z * x.z + x.w * x.w;
    }
    ss += __shfl_xor(ss, 1, 64);
    if (!halfA) scl[rowA] = rsqrtf(ss * (1.f / 256.f) + EPS);
  }

  f32x4 acc[2][4];
  #pragma unroll
  for (int p = 0; p < 2; ++p)
    #pragma unroll
    for (int q = 0; q < 4; ++q) acc[p][q] = (f32x4)0.f;

  for (int kb = 0; kb < 4; ++kb) {
    __syncthreads();
    {
      const int row = tid >> 1, tk0 = (tid & 1) * 32;
      const float4* pB = (const float4*)(m + (size_t)growA * CM + kb * 64 + tk0);
      const float4* pG = (const float4*)(gin + kb * 64 + tk0);
      float sc = scl[row];
      #pragma unroll
      for (int u = 0; u < 4; ++u) {
        float4 x0 = pB[u * 2], x1 = pB[u * 2 + 1];
        float4 g0 = pG[u * 2], g1 = pG[u * 2 + 1];
        union { unsigned short h[8]; int4 q; } pk;
        pk.h[0] = f2bf(x0.x * sc * g0.x); pk.h[1] = f2bf(x0.y * sc * g0.y);
        pk.h[2] = f2bf(x0.z * sc * g0.z); pk.h[3] = f2bf(x0.w * sc * g0.w);
        pk.h[4] = f2bf(x1.x * sc * g1.x); pk.h[5] = f2bf(x1.y * sc * g1.y);
        pk.h[6] = f2bf(x1.z * sc * g1.z); pk.h[7] = f2bf(x1.w * sc * g1.w);
        int blkid = (((tid & 1) * 4 + u) ^ (row & 7));
        *(int4*)(smem + row * 128 + blkid * 16) = pk.q;
      }
    }
    __syncthreads();
    #pragma unroll
    for (int ks = 0; ks < 2; ++ks) {
      bf16x8 af[2], bfr[4];
      int k8 = ks * 4 + quad;
      #pragma unroll
      for (int fm = 0; fm < 2; ++fm) {
        int mm = w * 32 + fm * 16 + mlo;
        af[fm] = *(const bf16x8*)(smem + mm * 128 + ((k8 ^ (mm & 7)) * 16));
      }
      #pragma unroll
      for (int fn = 0; fn < 4; ++fn) {
        int c = fn * 16 + mlo;
        int t8 = kb * 8 + ks * 4 + quad;
        bfr[fn] = *(const bf16x8*)(smem + 16384 + c * 512 + (((t8 & ~7) | ((t8 & 7) ^ (c & 7))) * 16));
      }
      #pragma unroll
      for (int fm = 0; fm < 2; ++fm)
        #pragma unroll
        for (int fn = 0; fn < 4; ++fn)
          acc[fm][fn] = __builtin_amdgcn_mfma_f32_16x16x32_bf16(af[fm], bfr[fn], acc[fm][fn], 0, 0, 0);
    }
  }
  __syncthreads();
  unsigned short* Cl = (unsigned short*)(smem + 49664);
  #pragma unroll
  for (int fm = 0; fm < 2; ++fm)
    #pragma unroll
    for (int fn = 0; fn < 4; ++fn) {
      int cc = fn * 16 + mlo;
      float bias = (cc < 32) ? bq[cc] : bk[cc - 32];
      #pragma unroll
      for (int r = 0; r < 4; ++r) {
        int rr = w * 32 + fm * 16 + quad * 4 + r;
        Cl[rr * 72 + cc] = f2bf(acc[fm][fn][r] + bias);
      }
    }
  __syncthreads();
  {
    int il = tid >> 6, cc = tid & 63;
    unsigned short* dst = (cc < 32) ? (qT + ((i0 + il) * 32 + cc) * BB + b0)
                                    : (kT + ((i0 + il) * 32 + (cc - 32)) * BB + b0);
    #pragma unroll
    for (int v = 0; v < 4; ++v) {
      union { unsigned short h[8]; int4 q; } u;
      #pragma unroll
      for (int x = 0; x < 8; ++x) u.h[x] = Cl[((v * 8 + x) * 4 + il) * 72 + cc];
      *(int4*)(dst + v * 8) = u.q;
    }
  }
}

// ---------------- K3: 256x128 O-tile GEMM -> @Wo + bo -> rmsnorm -> z -------------------------------
// 512 threads = 8 waves in 4x2 (wm x wn); wave-tile 64x64, frags 4x4. 32 ij rows per block:
// WoT (256KB) streamed ONCE per 32 output rows (was once per 16) — halves the dominant L2 traffic.
__global__ __launch_bounds__(512, 4) void k3_fused(const unsigned short* __restrict__ qT,
                                                   const unsigned short* __restrict__ kT,
                                                   const unsigned short* __restrict__ WoTp,
                                                   const float* __restrict__ bo,
                                                   const float* __restrict__ gout,
                                                   float* __restrict__ out) {
  // LDS 64KB: GEMM1: A-tile [256][64] swz @0 (32KB) | B-tile [128][64] swz @32768 (16KB).
  // After GEMM1 the whole 64KB aliases O_lds [32 ij][1024 k2'] bf16 (k2' = d*32+c, swizzled).
  // After stage-2 reads complete, [0,1280) aliases red[32][8] f32 + scl[32].
  __shared__ char smem[65536] __attribute__((aligned(16)));
  const int tid = threadIdx.x;
  const int w = tid >> 6, lane = tid & 63;
  const int wm = w & 3, wn = w >> 2;          // wave grid 4 (m) x 2 (n)
  const int ti = blockIdx.x, tj = blockIdx.y; // ti: 48 tiles of 256 rows; tj: 96 tiles of 128
  const int mlo = lane & 15, quad = lane >> 4;

  f32x4 acc[4][4];
  #pragma unroll
  for (int p = 0; p < 4; ++p)
    #pragma unroll
    for (int q = 0; q < 4; ++q) acc[p][q] = (f32x4)0.f;

  // -------- GEMM1: O[m][n] = sum_b qT[ti*256+m][b] * kT[tj*128+n][b], K=256, BK=64 --------
  for (int kb = 0; kb < 4; ++kb) {
    __syncthreads();
    #pragma unroll
    for (int s = 0; s < 4; ++s) {            // A-tile: wave w stages rows [w*32, w*32+32)
      int r = w * 32 + s * 8 + (lane >> 3);
      int k8 = (lane & 7) ^ (r & 7);
      gload_lds16(qT + (ti * 256 + r) * BB + kb * 64 + k8 * 8, smem, (uint32_t)(w * 32 + s * 8) * 128u);
    }
    #pragma unroll
    for (int s = 0; s < 2; ++s) {            // B-tile: wave w stages rows [w*16, w*16+16)
      int r = w * 16 + s * 8 + (lane >> 3);
      int k8 = (lane & 7) ^ (r & 7);
      gload_lds16(kT + (tj * 128 + r) * BB + kb * 64 + k8 * 8, smem, 32768u + (uint32_t)(w * 16 + s * 8) * 128u);
    }
    asm volatile("s_waitcnt vmcnt(0)" ::: "memory");
    __syncthreads();
    #pragma unroll
    for (int ks = 0; ks < 2; ++ks) {
      bf16x8 af[4], bfr[4];
      int k8 = ks * 4 + quad;
      #pragma unroll
      for (int f = 0; f < 4; ++f) {
        int mm = wm * 64 + f * 16 + mlo;
        af[f] = *(const bf16x8*)(smem + mm * 128 + ((k8 ^ (mm & 7)) * 16));
        int nn = wn * 64 + f * 16 + mlo;
        bfr[f] = *(const bf16x8*)(smem + 32768 + nn * 128 + ((k8 ^ (nn & 7)) * 16));
      }
      #pragma unroll
      for (int fm = 0; fm < 4; ++fm)
        #pragma unroll
        for (int fn = 0; fn < 4; ++fn)
          acc[fm][fn] = __builtin_amdgcn_mfma_f32_16x16x32_bf16(af[fm], bfr[fn], acc[fm][fn], 0, 0, 0);
    }
  }
  __syncthreads();   // A/B tiles consumed; O_lds aliases the full 64KB

  // -------- O (C-layout regs) -> O_lds[ij][k2'] bf16, k2' = d*32 + c; packed 8B writes --------
  #pragma unroll
  for (int fm = 0; fm < 4; ++fm)
    #pragma unroll
    for (int fn = 0; fn < 4; ++fn) {
      int col = wn * 64 + fn * 16 + mlo;                 // n = jloc*32 + d  (0..127)
      int row0 = wm * 64 + fm * 16 + quad * 4;           // m = iloc*32 + c  (0..255)
      int ij = (row0 >> 5) * 4 + (col >> 5);             // iloc*4 + jloc    (0..31)
      int k20 = (col & 31) * 32 + (row0 & 31);           // d*32 + c
      int blk = k20 >> 3;
      int off = ij * 2048 + (((blk & ~7) | ((blk & 7) ^ (ij & 7))) * 16) + (k20 & 7) * 2;
      union { unsigned short h[4]; uint2 u; } pk;
      #pragma unroll
      for (int r = 0; r < 4; ++r) pk.h[r] = f2bf(acc[fm][fn][r]);
      *(uint2*)(smem + off) = pk.u;
    }
  __syncthreads();

  // -------- stage 2: z[32 ij][128 e] = O @ Wo; wave w owns e-slice [w*16, w*16+16) --------
  const int e = w * 16 + mlo;
  const unsigned short* wrow = WoTp + (size_t)e * 1024;
  f32x4 acc2[4];                              // [f*2 + kk-parity], f = ij-frag (0: ij<16, 1: ij>=16)
  #pragma unroll
  for (int p = 0; p < 4; ++p) acc2[p] = (f32x4)0.f;
  #pragma unroll 4
  for (int kk = 0; kk < 32; ++kk) {
    int k = kk * 32 + quad * 8;
    int blk = kk * 4 + quad;
    bf16x8 b = *(const bf16x8*)(wrow + k);    // one WoT frag feeds 2 MFMAs
    #pragma unroll
    for (int f = 0; f < 2; ++f) {
      int ij = f * 16 + mlo;
      bf16x8 a = *(const bf16x8*)(smem + ij * 2048 + (((blk & ~7) | ((blk & 7) ^ (ij & 7))) * 16));
      acc2[f * 2 + (kk & 1)] = __builtin_amdgcn_mfma_f32_16x16x32_bf16(a, b, acc2[f * 2 + (kk & 1)], 0, 0, 0);
    }
  }

  // -------- + bo, rmsnorm over e per (i,j), write out --------
  // acc2 C-layout: z[ij = f*16 + quad*4 + r][e = w*16 + mlo]
  float bv = bo[e], gv = gout[e];
  float v[2][4], sq[2][4];
  #pragma unroll
  for (int f = 0; f < 2; ++f)
    #pragma unroll
    for (int r = 0; r < 4; ++r) {
      v[f][r] = acc2[f * 2][r] + acc2[f * 2 + 1][r] + bv;
      sq[f][r] = v[f][r] * v[f][r];
    }
  #pragma unroll
  for (int o = 1; o < 16; o <<= 1)
    #pragma unroll
    for (int f = 0; f < 2; ++f)
      #pragma unroll
      for (int r = 0; r < 4; ++r) sq[f][r] += __shfl_xor(sq[f][r], o, 64);

  __syncthreads();                       // all O_lds reads done; red/scl alias smem
  float* red = (float*)smem;             // [32 ij][8 wave]
  float* sclp = (float*)(smem + 1024);   // [32]
  if (mlo == 0) {
    #pragma unroll
    for (int f = 0; f < 2; ++f)
      #pragma unroll
      for (int r = 0; r < 4; ++r) red[(f * 16 + quad * 4 + r) * 8 + w] = sq[f][r];
  }
  __syncthreads();
  if (tid < 32) {
    float s = 0.f;
    #pragma unroll
    for (int p = 0; p < 8; ++p) s += red[tid * 8 + p];
    sclp[tid] = rsqrtf(s * (1.f / 128.f) + EPS);
  }
  __syncthreads();
  #pragma unroll
  for (int f = 0; f < 2; ++f)
    #pragma unroll
    for (int r = 0; r < 4; ++r) {
      int ij = f * 16 + quad * 4 + r;
      float sc = sclp[ij];
      int gi = ti * 8 + (ij >> 2), gj = tj * 4 + (ij & 3);
      out[((size_t)gi * S + gj) * CZ + e] = v[f][r] * sc * gv;
    }
}

// ---------------------------------------------------------------------------------------------------
extern "C" void kernel_launch(void* const* d_in, const int* in_sizes, int n_in,
                              void* d_out, int out_size, void* d_ws, size_t ws_size,
                              hipStream_t stream) {
  const float* m    = (const float*)d_in[0];
  const float* gin  = (const float*)d_in[1];
  const float* Wq   = (const float*)d_in[2];
  const float* bq   = (const float*)d_in[3];
  const float* Wk   = (const float*)d_in[4];
  const float* bk   = (const float*)d_in[5];
  const float* Wo   = (const float*)d_in[6];
  const float* bo   = (const float*)d_in[7];
  const float* gout = (const float*)d_in[8];

  char* ws = (char*)d_ws;
  unsigned short* qT    = (unsigned short*)(ws + OFF_QT);
  unsigned short* kT    = (unsigned short*)(ws + OFF_KT);
  unsigned short* WTg   = (unsigned short*)(ws + OFF_WT);
  unsigned short* WoTp  = (unsigned short*)(ws + OFF_WOT);
  float* out = (float*)d_out;

  hipLaunchKernelGGL(k0_prep, dim3(576), dim3(256), 0, stream, Wq, Wk, Wo, WTg, WoTp);
  hipLaunchKernelGGL(k2_proj, dim3(96, 8), dim3(256), 0, stream, m, gin, WTg, bq, bk, qT, kT);
  hipLaunchKernelGGL(k3_fused, dim3(48, 96), dim3(512), 0, stream, qT, kT, WoTp, bo, gout, out);
}